// Round 1
// baseline (378.140 us; speedup 1.0000x reference)
//
#include <hip/hip_runtime.h>
#include <cstdint>
#include <cstddef>

typedef unsigned short u16;
typedef __attribute__((ext_vector_type(8))) short s16x8;
typedef __attribute__((ext_vector_type(4))) float f32x4;

#define DEV __device__ __forceinline__

DEV float bf2f(short u){
  union { unsigned int i; float f; } v;
  v.i = ((unsigned int)(u16)u) << 16;
  return v.f;
}
DEV short f2bf(float f){
  union { float f; unsigned int i; } v; v.f = f;
  unsigned int u = v.i;
  u += 0x7fffu + ((u >> 16) & 1u);   // RNE
  return (short)(u >> 16);
}
DEV s16x8 s16x8_zero(){
  s16x8 z;
#pragma unroll
  for(int j=0;j<8;j++) z[j]=0;
  return z;
}
DEV f32x4 f32x4_zero(){
  f32x4 z;
#pragma unroll
  for(int j=0;j<4;j++) z[j]=0.f;
  return z;
}
DEV f32x4 mfma16(s16x8 a, s16x8 b, f32x4 c){
  return __builtin_amdgcn_mfma_f32_16x16x32_bf16(a, b, c, 0, 0, 0);
}

// ---------------- problem constants ----------------
// B=4, Cin=512 (concat), H=W=64, P=9 taps, Cout=256, M = B*H*W = 16384
// workspace layout (bytes), all 256B-aligned
static constexpr size_t OFF_ACC_B  = 0;                        // float[16384*32]
static constexpr size_t OUT1_ACC_B = 2097152;                  // float[16384*256]
static constexpr size_t OUT2_ACC_B = OUT1_ACC_B + 16777216;    // float[16384*256]
static constexpr size_t STATS_B    = OUT2_ACC_B + 16777216;    // float[1024]
static constexpr size_t ZERO_BYTES = STATS_B + 4096;
static constexpr size_t XN_B       = ZERO_BYTES;               // u16[16384*512]
static constexpr size_t OUT1N_B    = XN_B + 16777216;          // u16[16384*256]
static constexpr size_t WOFFT_B    = OUT1N_B + 8388608;        // u16[32*4608]
static constexpr size_t WDCNT_B    = WOFFT_B + 294912;         // u16[256*4608]
static constexpr size_t W2T_B      = WDCNT_B + 2359296;        // u16[256*2304]
// total ~61.7 MB

// ---------------- NCHW fp32 (concat) -> NHWC bf16 ----------------
__global__ void k_x_to_nhwc(const float* __restrict__ v, const float* __restrict__ vi,
                            u16* __restrict__ xn){
  __shared__ float tile[64][65];
  const int b = blockIdx.z, c0 = blockIdx.y*64, hw0 = blockIdx.x*64;
  const float* src = (c0 < 256) ? (v  + ((size_t)b*256 + c0)      *4096)
                                : (vi + ((size_t)b*256 + (c0-256))*4096);
  const int t = threadIdx.x;
#pragma unroll
  for(int k=0;k<16;k++){
    int idx = t + k*256;
    int cl = idx >> 6, wl = idx & 63;
    tile[cl][wl] = src[(size_t)cl*4096 + hw0 + wl];
  }
  __syncthreads();
#pragma unroll
  for(int k=0;k<16;k++){
    int idx = t + k*256;
    int wl = idx >> 6, cl = idx & 63;
    xn[(size_t)(b*4096 + hw0 + wl)*512 + c0 + cl] = (u16)f2bf(tile[cl][wl]);
  }
}

// ---------------- weight repacks: OIHW fp32 -> [N][K] bf16, K = tap*C + c ----------------
__global__ void k_prep_woff(const float* __restrict__ w, u16* __restrict__ wt){
  int idx = blockIdx.x*256 + threadIdx.x;
  if(idx >= 32*4608) return;
  int n = idx / 4608, k = idx % 4608;
  int t = k >> 9, c = k & 511;
  float val = (n < 27) ? w[(size_t)(n*512 + c)*9 + t] : 0.f;
  wt[idx] = (u16)f2bf(val);
}
__global__ void k_prep_wdcn(const float* __restrict__ w, u16* __restrict__ wt){
  int idx = blockIdx.x*256 + threadIdx.x;
  if(idx >= 256*4608) return;
  int n = idx / 4608, k = idx % 4608;
  int t = k >> 9, c = k & 511;
  wt[idx] = (u16)f2bf(w[(size_t)(n*512 + c)*9 + t]);
}
__global__ void k_prep_w2(const float* __restrict__ w, u16* __restrict__ wt){
  int idx = blockIdx.x*256 + threadIdx.x;
  if(idx >= 256*2304) return;
  int n = idx / 2304, k = idx % 2304;
  int t = k >> 8, c = k & 255;
  wt[idx] = (u16)f2bf(w[(size_t)(n*256 + c)*9 + t]);
}

// ---------------- offset conv: 512ch -> 27(pad 32), implicit GEMM ----------------
// grid (128 m-tiles of 128, 4 k-splits by taps {0,2},{2,4},{4,6},{6,9})
__global__ __launch_bounds__(256, 2) void k_conv_off(
    const u16* __restrict__ xn, const u16* __restrict__ wt, float* __restrict__ offa){
  __shared__ short A_lds[4][128][8];   // [k/8][row][8]
  __shared__ short B_lds[4][32][8];
  const int tid = threadIdx.x;
  const int lane = tid & 63, wid = tid >> 6;
  const int quad = lane >> 4, ln = lane & 15;
  const int m0 = blockIdx.x * 128;
  const int b = m0 >> 12;
  const int h0 = (m0 & 4095) >> 6;
  const int ks = blockIdx.y;
  const int ts0 = (ks==0)?0:(ks==1)?2:(ks==2)?4:6;
  const int ts1 = (ks==0)?2:(ks==1)?4:(ks==2)?6:9;
  const int m_base = wid * 32;
  const int r = tid >> 1, sp = (tid & 1) * 2;
  const int h_r = h0 + (r >> 6), w_r = r & 63;
  const s16x8* Ap = (const s16x8*)A_lds;
  const s16x8* Bp = (const s16x8*)B_lds;
  f32x4 acc[2][2];
#pragma unroll
  for(int mf=0;mf<2;mf++)
#pragma unroll
    for(int nf=0;nf<2;nf++) acc[mf][nf] = f32x4_zero();

  for(int tp=ts0; tp<ts1; tp++){
    const int ty = tp/3, tx = tp - ty*3;
    const int y = h_r - 1 + ty, x = w_r - 1 + tx;
    const bool vld = (y>=0) & (y<64) & (x>=0) & (x<64);
    const u16* src = xn + (long)(b*4096 + y*64 + x)*512 + sp*8;
    const int kbase = tp*512;
    for(int cc=0; cc<16; cc++){
      const int c0 = cc*32;
      s16x8 v0 = s16x8_zero(), v1 = s16x8_zero();
      if(vld){
        v0 = *(const s16x8*)(src + c0);
        v1 = *(const s16x8*)(src + c0 + 8);
      }
      *(s16x8*)(&A_lds[sp][r][0])   = v0;
      *(s16x8*)(&A_lds[sp+1][r][0]) = v1;
      if(tid < 128){
        const int n = tid & 31, s2 = tid >> 5;
        *(s16x8*)(&B_lds[s2][n][0]) =
            *(const s16x8*)(wt + (size_t)n*4608 + kbase + c0 + s2*8);
      }
      __syncthreads();
      s16x8 a0 = Ap[quad*128 + m_base + ln];
      s16x8 a1 = Ap[quad*128 + m_base + 16 + ln];
      s16x8 b0 = Bp[quad*32 + ln];
      s16x8 b1 = Bp[quad*32 + 16 + ln];
      acc[0][0] = mfma16(a0, b0, acc[0][0]);
      acc[0][1] = mfma16(a0, b1, acc[0][1]);
      acc[1][0] = mfma16(a1, b0, acc[1][0]);
      acc[1][1] = mfma16(a1, b1, acc[1][1]);
      __syncthreads();
    }
  }
#pragma unroll
  for(int mf=0;mf<2;mf++)
#pragma unroll
    for(int nf=0;nf<2;nf++){
      const int col = nf*16 + ln;
#pragma unroll
      for(int i=0;i<4;i++){
        const int row = m_base + mf*16 + quad*4 + i;
        unsafeAtomicAdd(offa + (size_t)(m0+row)*32 + col, acc[mf][nf][i]);
      }
    }
}

// ---------------- DCN main: bilinear-sample A rows, GEMM vs w_dcn ----------------
// grid (256 m-tiles of 64, 2 k-splits by taps {0..3},{4..8}); block 64x256 tile
__global__ __launch_bounds__(256, 2) void k_dcn(
    const u16* __restrict__ xn, const u16* __restrict__ wt,
    const float* __restrict__ offa, const float* __restrict__ boff,
    float* __restrict__ outa){
  __shared__ short A_lds[4][64][8];
  __shared__ short B_lds[4][256][8];
  __shared__ int   p_ofs[4][64];
  __shared__ float p_wgt[4][64];
  const int tid = threadIdx.x;
  const int lane = tid & 63, wid = tid >> 6;
  const int quad = lane >> 4, ln = lane & 15;
  const int m0 = blockIdx.x * 64;
  const int b = m0 >> 12;
  const int h = (m0 & 4095) >> 6;
  const int ts0 = blockIdx.y ? 4 : 0;
  const int ts1 = blockIdx.y ? 9 : 4;
  const int wm = wid >> 1, wn = wid & 1;
  const int m_base = wm*32, n_base = wn*128;
  const int r = tid >> 2, sub = tid & 3;
  const s16x8* Ap = (const s16x8*)A_lds;
  const s16x8* Bp = (const s16x8*)B_lds;
  f32x4 acc[2][8];
#pragma unroll
  for(int mf=0;mf<2;mf++)
#pragma unroll
    for(int nf=0;nf<8;nf++) acc[mf][nf] = f32x4_zero();

  for(int tp=ts0; tp<ts1; tp++){
    if(tid < 64){
      const int rr = tid;
      const float* orow = offa + (size_t)(m0+rr)*32;
      float dy = orow[2*tp]   + boff[2*tp];
      float dx = orow[2*tp+1] + boff[2*tp+1];
      float mz = orow[18+tp]  + boff[18+tp];
      float mk = 1.f / (1.f + expf(-mz));               // modulation mask
      float ypos = (float)(h - 1 + tp/3) + dy;
      float xpos = (float)(rr - 1 + tp%3) + dx;
      float y0f = floorf(ypos), x0f = floorf(xpos);
      float ly = ypos - y0f, lx = xpos - x0f;
      int y0 = (int)y0f, x0 = (int)x0f;
#pragma unroll
      for(int k=0;k<4;k++){
        int ddy = k >> 1, ddx = k & 1;
        int yi = y0 + ddy, xi = x0 + ddx;
        bool vv = (yi >= 0) & (yi < 64) & (xi >= 0) & (xi < 64);
        float wk = (ddy ? ly : 1.f-ly) * (ddx ? lx : 1.f-lx) * mk;
        if(!vv) wk = 0.f;
        int yc = yi < 0 ? 0 : (yi > 63 ? 63 : yi);
        int xc = xi < 0 ? 0 : (xi > 63 ? 63 : xi);
        p_ofs[k][rr] = ((b << 12) + (yc << 6) + xc) << 9;  // *512 channels
        p_wgt[k][rr] = wk;
      }
    }
    __syncthreads();
    const float w0f = p_wgt[0][r], w1f = p_wgt[1][r], w2f = p_wgt[2][r], w3f = p_wgt[3][r];
    const u16* s0p = xn + p_ofs[0][r] + sub*8;
    const u16* s1p = xn + p_ofs[1][r] + sub*8;
    const u16* s2p = xn + p_ofs[2][r] + sub*8;
    const u16* s3p = xn + p_ofs[3][r] + sub*8;
    const u16* wrow0 = wt + (size_t)tid*4608 + tp*512;

    for(int cc=0; cc<16; cc++){
      const int c0 = cc*32;
      s16x8 v0 = *(const s16x8*)(s0p + c0);
      s16x8 v1 = *(const s16x8*)(s1p + c0);
      s16x8 v2 = *(const s16x8*)(s2p + c0);
      s16x8 v3 = *(const s16x8*)(s3p + c0);
      s16x8 pk;
#pragma unroll
      for(int j=0;j<8;j++){
        float f = w0f * bf2f(v0[j]);
        f = fmaf(w1f, bf2f(v1[j]), f);
        f = fmaf(w2f, bf2f(v2[j]), f);
        f = fmaf(w3f, bf2f(v3[j]), f);
        pk[j] = f2bf(f);
      }
      *(s16x8*)(&A_lds[sub][r][0]) = pk;
#pragma unroll
      for(int s2=0; s2<4; s2++)
        *(s16x8*)(&B_lds[s2][tid][0]) = *(const s16x8*)(wrow0 + c0 + s2*8);
      __syncthreads();
      s16x8 af0 = Ap[quad*64 + m_base + ln];
      s16x8 af1 = Ap[quad*64 + m_base + 16 + ln];
      s16x8 bfr[8];
#pragma unroll
      for(int nf=0;nf<8;nf++) bfr[nf] = Bp[quad*256 + n_base + nf*16 + ln];
#pragma unroll
      for(int nf=0;nf<8;nf++){
        acc[0][nf] = mfma16(af0, bfr[nf], acc[0][nf]);
        acc[1][nf] = mfma16(af1, bfr[nf], acc[1][nf]);
      }
      __syncthreads();
    }
  }
#pragma unroll
  for(int mf=0;mf<2;mf++)
#pragma unroll
    for(int nf=0;nf<8;nf++){
      const int col = n_base + nf*16 + ln;
#pragma unroll
      for(int i=0;i<4;i++){
        const int row = m_base + mf*16 + quad*4 + i;
        unsafeAtomicAdd(outa + (size_t)(m0+row)*256 + col, acc[mf][nf][i]);
      }
    }
}

// ---------------- conv2: 256 -> 256, implicit GEMM on normalized out1 ----------------
__global__ __launch_bounds__(256, 2) void k_conv2(
    const u16* __restrict__ a_in, const u16* __restrict__ wt, float* __restrict__ outa){
  __shared__ short A_lds[4][64][8];
  __shared__ short B_lds[4][256][8];
  const int tid = threadIdx.x;
  const int lane = tid & 63, wid = tid >> 6;
  const int quad = lane >> 4, ln = lane & 15;
  const int m0 = blockIdx.x * 64;
  const int b = m0 >> 12;
  const int h = (m0 & 4095) >> 6;
  const int ts0 = blockIdx.y ? 4 : 0;
  const int ts1 = blockIdx.y ? 9 : 4;
  const int wm = wid >> 1, wn = wid & 1;
  const int m_base = wm*32, n_base = wn*128;
  const int r = tid >> 2, sub = tid & 3;
  const s16x8* Ap = (const s16x8*)A_lds;
  const s16x8* Bp = (const s16x8*)B_lds;
  f32x4 acc[2][8];
#pragma unroll
  for(int mf=0;mf<2;mf++)
#pragma unroll
    for(int nf=0;nf<8;nf++) acc[mf][nf] = f32x4_zero();

  for(int tp=ts0; tp<ts1; tp++){
    const int ty = tp/3, tx = tp - ty*3;
    const int y = h - 1 + ty, x = r - 1 + tx;
    const bool vld = (y>=0) & (y<64) & (x>=0) & (x<64);
    const u16* src = a_in + (long)(b*4096 + y*64 + x)*256 + sub*8;
    const u16* wrow0 = wt + (size_t)tid*2304 + tp*256;
    for(int cc=0; cc<8; cc++){
      const int c0 = cc*32;
      s16x8 va = vld ? *(const s16x8*)(src + c0) : s16x8_zero();
      *(s16x8*)(&A_lds[sub][r][0]) = va;
#pragma unroll
      for(int s2=0;s2<4;s2++)
        *(s16x8*)(&B_lds[s2][tid][0]) = *(const s16x8*)(wrow0 + c0 + s2*8);
      __syncthreads();
      s16x8 af0 = Ap[quad*64 + m_base + ln];
      s16x8 af1 = Ap[quad*64 + m_base + 16 + ln];
      s16x8 bfr[8];
#pragma unroll
      for(int nf=0;nf<8;nf++) bfr[nf] = Bp[quad*256 + n_base + nf*16 + ln];
#pragma unroll
      for(int nf=0;nf<8;nf++){
        acc[0][nf] = mfma16(af0, bfr[nf], acc[0][nf]);
        acc[1][nf] = mfma16(af1, bfr[nf], acc[1][nf]);
      }
      __syncthreads();
    }
  }
#pragma unroll
  for(int mf=0;mf<2;mf++)
#pragma unroll
    for(int nf=0;nf<8;nf++){
      const int col = n_base + nf*16 + ln;
#pragma unroll
      for(int i=0;i<4;i++){
        const int row = m_base + mf*16 + quad*4 + i;
        unsafeAtomicAdd(outa + (size_t)(m0+row)*256 + col, acc[mf][nf][i]);
      }
    }
}

// ---------------- BN stats: per-channel sum/sumsq over M=16384 ----------------
__global__ void k_stats(const float* __restrict__ acc, float* __restrict__ sum,
                        float* __restrict__ sq){
  const int m0 = blockIdx.x*64;
  const int c = threadIdx.x;
  float s = 0.f, q = 0.f;
  for(int i=0;i<64;i++){
    float v = acc[(size_t)(m0+i)*256 + c];
    s += v; q += v*v;
  }
  unsafeAtomicAdd(sum + c, s);
  unsafeAtomicAdd(sq + c, q);
}

// ---------------- BN1 + ReLU -> bf16 NHWC ----------------
__global__ void k_bn1(const float* __restrict__ acc, const float* __restrict__ sum,
                      const float* __restrict__ sq, const float* __restrict__ g,
                      const float* __restrict__ bt, u16* __restrict__ o){
  __shared__ float sc[256], sh[256];
  const int t = threadIdx.x;
  {
    float mean = sum[t] * (1.f/16384.f);
    float var  = sq[t] * (1.f/16384.f) - mean*mean;
    float rstd = rsqrtf(var + 1e-5f);
    float s = g[t] * rstd;
    sc[t] = s; sh[t] = bt[t] - mean*s;
  }
  __syncthreads();
  const int c4 = (t & 63) * 4;
  const float s0 = sc[c4], s1 = sc[c4+1], s2 = sc[c4+2], s3 = sc[c4+3];
  const float h0 = sh[c4], h1 = sh[c4+1], h2 = sh[c4+2], h3 = sh[c4+3];
#pragma unroll
  for(int k=0;k<4;k++){
    int m = blockIdx.x*16 + k*4 + (t>>6);
    const float4 v = *(const float4*)(acc + (size_t)m*256 + c4);
    unsigned int lo = (unsigned int)(u16)f2bf(fmaxf(0.f, v.x*s0 + h0))
                    | ((unsigned int)(u16)f2bf(fmaxf(0.f, v.y*s1 + h1)) << 16);
    unsigned int hi = (unsigned int)(u16)f2bf(fmaxf(0.f, v.z*s2 + h2))
                    | ((unsigned int)(u16)f2bf(fmaxf(0.f, v.w*s3 + h3)) << 16);
    uint2 pr; pr.x = lo; pr.y = hi;
    *(uint2*)(o + (size_t)m*256 + c4) = pr;
  }
}

// ---------------- BN2 + ReLU + NHWC->NCHW fp32 output ----------------
__global__ void k_bn2_out(const float* __restrict__ acc, const float* __restrict__ sum,
                          const float* __restrict__ sq, const float* __restrict__ g,
                          const float* __restrict__ bt, float* __restrict__ out){
  __shared__ float tile[64][65];
  __shared__ float sc[64], sh[64];
  const int t = threadIdx.x;
  const int b = blockIdx.z, c0 = blockIdx.y*64, hw0 = blockIdx.x*64;
  if(t < 64){
    int c = c0 + t;
    float mean = sum[c] * (1.f/16384.f);
    float var  = sq[c] * (1.f/16384.f) - mean*mean;
    float rstd = rsqrtf(var + 1e-5f);
    float s = g[c] * rstd;
    sc[t] = s; sh[t] = bt[c] - mean*s;
  }
  __syncthreads();
#pragma unroll
  for(int k=0;k<16;k++){
    int idx = t + k*256;
    int wl = idx >> 6, cl = idx & 63;
    float v = acc[(size_t)((b<<12) + hw0 + wl)*256 + c0 + cl];
    tile[wl][cl] = fmaxf(0.f, v*sc[cl] + sh[cl]);
  }
  __syncthreads();
#pragma unroll
  for(int k=0;k<16;k++){
    int idx = t + k*256;
    int cl = idx >> 6, wl = idx & 63;
    out[(size_t)(b*256 + c0 + cl)*4096 + hw0 + wl] = tile[wl][cl];
  }
}

extern "C" void kernel_launch(void* const* d_in, const int* in_sizes, int n_in,
                              void* d_out, int out_size, void* d_ws, size_t ws_size,
                              hipStream_t stream){
  const float* in_v  = (const float*)d_in[0];
  const float* in_i  = (const float*)d_in[1];
  const float* w_off = (const float*)d_in[2];
  const float* b_off = (const float*)d_in[3];
  const float* w_dcn = (const float*)d_in[4];
  const float* g1    = (const float*)d_in[5];
  const float* bt1   = (const float*)d_in[6];
  const float* w2    = (const float*)d_in[7];
  const float* g2    = (const float*)d_in[8];
  const float* bt2   = (const float*)d_in[9];
  float* out = (float*)d_out;
  char* ws = (char*)d_ws;

  float* off_acc  = (float*)(ws + OFF_ACC_B);
  float* out1_acc = (float*)(ws + OUT1_ACC_B);
  float* out2_acc = (float*)(ws + OUT2_ACC_B);
  float* stats    = (float*)(ws + STATS_B);
  float* sum1 = stats,       *sq1 = stats + 256;
  float* sum2 = stats + 512, *sq2 = stats + 768;
  u16* xn    = (u16*)(ws + XN_B);
  u16* out1n = (u16*)(ws + OUT1N_B);
  u16* wofft = (u16*)(ws + WOFFT_B);
  u16* wdcnt = (u16*)(ws + WDCNT_B);
  u16* w2t   = (u16*)(ws + W2T_B);

  hipMemsetAsync(ws, 0, ZERO_BYTES, stream);
  k_x_to_nhwc<<<dim3(64,8,4), 256, 0, stream>>>(in_v, in_i, xn);
  k_prep_woff<<<576, 256, 0, stream>>>(w_off, wofft);
  k_prep_wdcn<<<4608, 256, 0, stream>>>(w_dcn, wdcnt);
  k_prep_w2<<<2304, 256, 0, stream>>>(w2, w2t);
  k_conv_off<<<dim3(128,4), 256, 0, stream>>>(xn, wofft, off_acc);
  k_dcn<<<dim3(256,2), 256, 0, stream>>>(xn, wdcnt, off_acc, b_off, out1_acc);
  k_stats<<<256, 256, 0, stream>>>(out1_acc, sum1, sq1);
  k_bn1<<<1024, 256, 0, stream>>>(out1_acc, sum1, sq1, g1, bt1, out1n);
  k_conv2<<<dim3(256,2), 256, 0, stream>>>(out1n, w2t, out2_acc);
  k_stats<<<256, 256, 0, stream>>>(out2_acc, sum2, sq2);
  k_bn2_out<<<dim3(64,4,4), 256, 0, stream>>>(out2_acc, sum2, sq2, g2, bt2, out);
}